// Round 13
// baseline (122.950 us; speedup 1.0000x reference)
//
#include <hip/hip_runtime.h>

typedef unsigned short u16;
typedef float f32x4 __attribute__((ext_vector_type(4)));
typedef __bf16 bfx8 __attribute__((ext_vector_type(8)));
typedef __bf16 bfx4 __attribute__((ext_vector_type(4)));
typedef u16 u16x8 __attribute__((ext_vector_type(8)));
typedef u16 u16x4 __attribute__((ext_vector_type(4)));

#define B_ 2
#define S_ 2048
#define E_ 1024
#define H_ 16
#define D_ 64

__device__ __forceinline__ u16 f2bf(float f) {
  unsigned u = __float_as_uint(f);
  u = u + 0x7FFFu + ((u >> 16) & 1u);  // RNE
  return (u16)(u >> 16);
}

// XOR swizzle for tiles with 128B rows: byte ^= ((row&7)<<4).
__device__ __forceinline__ int swz128(int o) { return o ^ ((o >> 3) & 0x70); }

// async global->LDS, 16B per lane; LDS dest is wave-uniform base (HW adds lane*16).
__device__ __forceinline__ void gload16(const void* g, void* l) {
  __builtin_amdgcn_global_load_lds((const __attribute__((address_space(1))) void*)g,
                                   (__attribute__((address_space(3))) void*)l, 16, 0, 0);
}

// Chunk table: 60 work items per (bh): (qi, t0, t1, slot), ordered ~longest-first.
// slot >= 0 -> partial chunk (needs merge); slot < 0 -> sole chunk, writes Y directly.
__device__ const signed char TQI[60] = {31, 31, 30, 30, 29, 29, 28, 28, 27, 27, 26, 26, 25, 25, 24,
                                        24, 23, 23, 22, 21, 20, 19, 18, 17, 16, 15, 14, 13, 12, 11,
                                        22, 10, 21, 9,  20, 8,  31, 19, 7,  30, 18, 6,  29, 17, 5,
                                        28, 16, 4,  27, 15, 3,  26, 14, 2,  25, 13, 1,  24, 12, 0};
__device__ const signed char TT0[60] = {0,  12, 0,  12, 0,  12, 0,  12, 0,  12, 0,  12, 0,  12, 0,
                                        12, 0,  12, 0,  0,  0,  0,  0,  0,  0,  0,  0,  0,  0,  0,
                                        12, 0,  12, 0,  12, 0,  24, 12, 0,  24, 12, 0,  24, 12, 0,
                                        24, 12, 0,  24, 12, 0,  24, 12, 0,  24, 12, 0,  24, 12, 0};
__device__ const signed char TT1[60] = {12, 24, 12, 24, 12, 24, 12, 24, 12, 24, 12, 24, 12, 24, 12,
                                        24, 12, 24, 12, 12, 12, 12, 12, 12, 12, 12, 12, 12, 12, 12,
                                        23, 11, 22, 10, 21, 9,  32, 20, 8,  31, 19, 7,  30, 18, 6,
                                        29, 17, 5,  28, 16, 4,  27, 15, 3,  26, 14, 2,  25, 13, 1};
__device__ const signed char TSL[60] = {45, 46, 42, 43, 39, 40, 36, 37, 33, 34, 30, 31, 27, 28, 24,
                                        25, 22, 23, 20, 18, 16, 14, 12, 10, 8,  6,  4,  2,  0,  -1,
                                        21, -1, 19, -1, 17, -1, 47, 15, -1, 44, 13, -1, 41, 11, -1,
                                        38, 9,  -1, 35, 7,  -1, 32, 5,  -1, 29, 3,  -1, 26, 1,  -1};

// ---------------- fused prep: x->bf16 convert + W_kqv^T + W_proj^T (bf16) ----------------
__global__ __launch_bounds__(256) void prep(const float* __restrict__ x,
                                            const float* __restrict__ Wk,
                                            const float* __restrict__ Wp, u16* __restrict__ xb,
                                            u16* __restrict__ wkt, u16* __restrict__ wpt) {
  __shared__ float tile[64][65];
  const int id = blockIdx.x, tid = threadIdx.x;
  if (id < 2048) {  // convert x: 2^20 float4 elements
    const float4* in4 = reinterpret_cast<const float4*>(x);
    u16x4* out4 = reinterpret_cast<u16x4*>(xb);
    int i = id * 256 + tid;
#pragma unroll
    for (int p = 0; p < 2; ++p, i += 524288) {
      const float4 v = in4[i];
      u16x4 o = {f2bf(v.x), f2bf(v.y), f2bf(v.z), f2bf(v.w)};
      out4[i] = o;
    }
    return;
  }
  const float* in;
  u16* out;
  int R, C, bx, by;
  if (id < 2816) {
    const int t = id - 2048;
    in = Wk; out = wkt; R = 1024; C = 3072; bx = t % 48; by = t / 48;
  } else {
    const int t = id - 2816;
    in = Wp; out = wpt; R = 1024; C = 1024; bx = t & 15; by = t >> 4;
  }
  const int ct = bx * 64, rt = by * 64;
#pragma unroll
  for (int p = 0; p < 4; ++p) {
    int f = p * 256 + tid;
    int row = f >> 4, c4 = (f & 15) << 2;
    const float4 v = *reinterpret_cast<const float4*>(in + (size_t)(rt + row) * C + ct + c4);
    tile[row][c4 + 0] = v.x; tile[row][c4 + 1] = v.y;
    tile[row][c4 + 2] = v.z; tile[row][c4 + 3] = v.w;
  }
  __syncthreads();
#pragma unroll
  for (int p = 0; p < 4; ++p) {
    int g = p * 256 + tid;
    int orow = g >> 4, k4 = (g & 15) << 2;
    u16x4 o = {f2bf(tile[k4 + 0][orow]), f2bf(tile[k4 + 1][orow]),
               f2bf(tile[k4 + 2][orow]), f2bf(tile[k4 + 3][orow])};
    *reinterpret_cast<u16x4*>(out + (size_t)(ct + orow) * R + rt + k4) = o;
  }
}

// ---------------- bf16 GEMM kqv (8 waves, 512 thr, dbuf): C = A @ Bt^T + bias ----------------
// K-loop transplanted from the validated gemm_proj dbuf structure (stage t+1 before compute t,
// one barrier/iter, loads in flight across barrier). Epilogue is the R9/R12-verbatim
// per-element scatter (84-VGPR-friendly store order; do NOT restructure — R10/R11 lesson),
// re-indexed for acc[4][2] (wave = wr x wc of 2x4, per-wave 64x32 output).
__global__ __launch_bounds__(512) void gemm_kqv(const u16* __restrict__ A,
                                                const u16* __restrict__ Bt,
                                                const float* __restrict__ bias, int M, int N, int K,
                                                u16* __restrict__ outK, u16* __restrict__ outQ,
                                                u16* __restrict__ outVt) {
  __shared__ __align__(16) u16 sA[2][8192];
  __shared__ __align__(16) u16 sB[2][8192];
  const int tid = threadIdx.x, lane = tid & 63;
  const int wave = tid >> 6, wr = wave >> 2, wc = wave & 3;  // 2x4 waves of 64x32
  int lin = blockIdx.y * gridDim.x + blockIdx.x;
  const int nwg = gridDim.x * gridDim.y;
  if ((nwg & 7) == 0) {  // bijective XCD-chunked swizzle
    const int cpx = nwg >> 3;
    lin = (lin & 7) * cpx + (lin >> 3);
  }
  const int bm = (lin / gridDim.x) * 128, bn = (lin % gridDim.x) * 128;
  const int r8 = lane >> 3, c16 = (lane & 7) ^ r8;
  f32x4 acc[4][2] = {};

  auto stage = [&](int k0, int buf) {
#pragma unroll
    for (int i = 0; i < 2; ++i) {
      const int c = wave * 2 + i;  // 16 chunks of 1KB
      const int row = c * 8 + r8;
      gload16(A + (size_t)(bm + row) * K + k0 + c16 * 8, (char*)sA[buf] + c * 1024);
      gload16(Bt + (size_t)(bn + row) * K + k0 + c16 * 8, (char*)sB[buf] + c * 1024);
    }
  };

  stage(0, 0);
  __syncthreads();
  int cur = 0;
  for (int k0 = 0; k0 < K; k0 += 64) {
    if (k0 + 64 < K) stage(k0 + 64, cur ^ 1);  // in flight across compute; drained at barrier
#pragma unroll
    for (int kc = 0; kc < 2; ++kc) {
      bfx8 af[4], bf[2];
#pragma unroll
      for (int mf = 0; mf < 4; ++mf) {
        int o = swz128(((wr * 64 + mf * 16 + (lane & 15)) << 7) + kc * 64 + ((lane >> 4) << 4));
        af[mf] = *reinterpret_cast<const bfx8*>(reinterpret_cast<const char*>(sA[cur]) + o);
      }
#pragma unroll
      for (int nf = 0; nf < 2; ++nf) {
        int o = swz128(((wc * 32 + nf * 16 + (lane & 15)) << 7) + kc * 64 + ((lane >> 4) << 4));
        bf[nf] = *reinterpret_cast<const bfx8*>(reinterpret_cast<const char*>(sB[cur]) + o);
      }
#pragma unroll
      for (int mf = 0; mf < 4; ++mf)
#pragma unroll
        for (int nf = 0; nf < 2; ++nf)
          acc[mf][nf] = __builtin_amdgcn_mfma_f32_16x16x32_bf16(af[mf], bf[nf], acc[mf][nf], 0, 0, 0);
    }
    __syncthreads();
    cur ^= 1;
  }
#pragma unroll
  for (int mf = 0; mf < 4; ++mf)
#pragma unroll
    for (int nf = 0; nf < 2; ++nf)
#pragma unroll
      for (int r = 0; r < 4; ++r) {
        const int row = bm + wr * 64 + mf * 16 + ((lane >> 4) << 2) + r;
        const int col = bn + wc * 32 + nf * 16 + (lane & 15);
        const float v = acc[mf][nf][r] + bias[col];
        const int chunk = col >> 10, w = col & 1023, h = w >> 6, dd = w & 63;
        const int b = row >> 11, s = row & 2047;
        const int bh = b * H_ + h;
        if (chunk == 0)
          outK[((size_t)bh * S_ + s) * D_ + dd] = f2bf(v);
        else if (chunk == 1)
          outQ[((size_t)bh * S_ + s) * D_ + dd] = f2bf(v);
        else
          outVt[((size_t)bh * D_ + dd) * S_ + s] = f2bf(v);  // fused V transpose
      }
}

// ---------------- proj GEMM (8 waves, 512 thr): fp32 out row-major ----------------
// Double-buffered global_load_lds staging (stage t+1 before compute t, one barrier/iter):
// at 1 block/CU there is no cross-block TLP, so prefetch must hide the load latency.
__global__ __launch_bounds__(512) void gemm_proj(const u16* __restrict__ A,
                                                 const u16* __restrict__ Bt,
                                                 const float* __restrict__ bias, int M, int N,
                                                 int K, float* __restrict__ outF) {
  __shared__ __align__(16) u16 sA[2][8192];
  __shared__ __align__(16) u16 sB[2][8192];
  const int tid = threadIdx.x, lane = tid & 63;
  const int wave = tid >> 6, wr = wave >> 2, wc = wave & 3;  // 2x4 waves of 64x32
  int lin = blockIdx.y * gridDim.x + blockIdx.x;
  const int nwg = gridDim.x * gridDim.y;
  if ((nwg & 7) == 0) {
    const int cpx = nwg >> 3;
    lin = (lin & 7) * cpx + (lin >> 3);
  }
  const int bm = (lin / gridDim.x) * 128, bn = (lin % gridDim.x) * 128;
  const int r8 = lane >> 3, c16 = (lane & 7) ^ r8;
  f32x4 acc[4][2] = {};

  auto stage = [&](int k0, int buf) {
#pragma unroll
    for (int i = 0; i < 2; ++i) {
      const int c = wave * 2 + i;  // 16 chunks of 1KB
      const int row = c * 8 + r8;
      gload16(A + (size_t)(bm + row) * K + k0 + c16 * 8, (char*)sA[buf] + c * 1024);
      gload16(Bt + (size_t)(bn + row) * K + k0 + c16 * 8, (char*)sB[buf] + c * 1024);
    }
  };

  stage(0, 0);
  __syncthreads();
  int cur = 0;
  for (int k0 = 0; k0 < K; k0 += 64) {
    if (k0 + 64 < K) stage(k0 + 64, cur ^ 1);  // in flight across compute; drained at barrier
#pragma unroll
    for (int kc = 0; kc < 2; ++kc) {
      bfx8 af[4], bf[2];
#pragma unroll
      for (int mf = 0; mf < 4; ++mf) {
        int o = swz128(((wr * 64 + mf * 16 + (lane & 15)) << 7) + kc * 64 + ((lane >> 4) << 4));
        af[mf] = *reinterpret_cast<const bfx8*>(reinterpret_cast<const char*>(sA[cur]) + o);
      }
#pragma unroll
      for (int nf = 0; nf < 2; ++nf) {
        int o = swz128(((wc * 32 + nf * 16 + (lane & 15)) << 7) + kc * 64 + ((lane >> 4) << 4));
        bf[nf] = *reinterpret_cast<const bfx8*>(reinterpret_cast<const char*>(sB[cur]) + o);
      }
#pragma unroll
      for (int mf = 0; mf < 4; ++mf)
#pragma unroll
        for (int nf = 0; nf < 2; ++nf)
          acc[mf][nf] = __builtin_amdgcn_mfma_f32_16x16x32_bf16(af[mf], bf[nf], acc[mf][nf], 0, 0, 0);
    }
    __syncthreads();
    cur ^= 1;
  }
#pragma unroll
  for (int mf = 0; mf < 4; ++mf)
#pragma unroll
    for (int nf = 0; nf < 2; ++nf)
#pragma unroll
      for (int r = 0; r < 4; ++r) {
        const int row = bm + wr * 64 + mf * 16 + ((lane >> 4) << 2) + r;
        const int col = bn + wc * 32 + nf * 16 + (lane & 15);
        outF[(size_t)row * N + col] = acc[mf][nf][r] + bias[col];
      }
}

// ---------------- flash attention with ALiBi, causal — split-KV chunked ----------------
// 1920 blocks = 8 XCD x 4 bh x 60 chunks; 4 blocks/CU resident, queue smooths imbalance.
// Sole chunks write Y; split chunks write unnormalized O + (m,l), merged by merge_attn.
__global__ __launch_bounds__(256, 4) void attn_alibi(const u16* __restrict__ Q,
                                                     const u16* __restrict__ Kb,
                                                     const u16* __restrict__ Vt,
                                                     const float* __restrict__ slopes,
                                                     u16* __restrict__ Y, u16* __restrict__ pO,
                                                     float* __restrict__ pML) {
  __shared__ __align__(16) u16 sK[2][4096];
  __shared__ __align__(16) u16 sV[2][4096];
  __shared__ __align__(16) __bf16 sP[4][16 * 64];
  const int id = blockIdx.x;
  const int xcd = id & 7, j = id >> 3;       // id%8 = XCD (round-robin dispatch)
  const int bh = xcd * 4 + (j & 3);          // 4 heads pinned per XCD (L2-resident K/V)
  const int c = j >> 2;                      // 0..59 chunk-table index
  const int qi = TQI[c], t0 = TT0[c], t1 = TT1[c], slot = TSL[c];
  const int b = bh >> 4, h = bh & 15;
  const int tid = threadIdx.x, lane = tid & 63, wave = tid >> 6;
  const int q = lane & 15, g = lane >> 4;
  const int q0 = qi * 64;
  const int w0 = q0 + wave * 16;
  const float L2E = 1.44269504089f;
  const float SCALE = 0.125f * L2E;
  const float sl2 = slopes[h] * L2E;
  const size_t headSD = (size_t)bh * (S_ * D_);
  const size_t headDS = (size_t)bh * (D_ * S_);
  const int r8 = lane >> 3, c16 = (lane & 7) ^ r8;

  bfx8 qf[2];
  {
    const u16* qp = Q + headSD + (size_t)(w0 + q) * D_ + g * 8;
    qf[0] = *reinterpret_cast<const bfx8*>(qp);
    qf[1] = *reinterpret_cast<const bfx8*>(qp + 32);
  }
  bfx8 onesf;
#pragma unroll
  for (int jj = 0; jj < 8; ++jj) onesf[jj] = (__bf16)1.0f;
  f32x4 base[4];
#pragma unroll
  for (int nf = 0; nf < 4; ++nf)
#pragma unroll
    for (int r = 0; r < 4; ++r) base[nf][r] = sl2 * (float)(nf * 16 + 4 * g + r);
  const int ir0 = wave * 16 + q;  // diagonal-tile mask boundary

  float m = 0.f;
  f32x4 oT[4] = {};
  f32x4 oX = {};  // l accumulator (all components equal l)

  auto stage = [&](int t, int buf) {
#pragma unroll
    for (int i = 0; i < 2; ++i) {
      const int cc = wave * 2 + i;
      const int row = cc * 8 + r8;
      gload16(Kb + headSD + (size_t)t * 4096 + row * 64 + c16 * 8, (char*)sK[buf] + cc * 1024);
      gload16(Vt + headDS + (size_t)row * S_ + t * 64 + c16 * 8, (char*)sV[buf] + cc * 1024);
    }
  };

  stage(t0, 0);
  __syncthreads();
  int cur = 0;
  for (int t = t0; t < t1; ++t) {
    if (t + 1 < t1) stage(t + 1, cur ^ 1);
    const char* sKc = reinterpret_cast<const char*>(sK[cur]);
    const char* sVc = reinterpret_cast<const char*>(sV[cur]);
    f32x4 tt[4] = {};
    __builtin_amdgcn_s_setprio(1);
#pragma unroll
    for (int kc = 0; kc < 2; ++kc)
#pragma unroll
      for (int nf = 0; nf < 4; ++nf) {
        const bfx8 kf =
            *reinterpret_cast<const bfx8*>(sKc + swz128(((nf * 16 + q) << 7) + kc * 64 + (g << 4)));
        tt[nf] = __builtin_amdgcn_mfma_f32_16x16x32_bf16(kf, qf[kc], tt[nf], 0, 0, 0);
      }
    __builtin_amdgcn_s_setprio(0);
    const float tb = sl2 * (float)(t * 64);
    if (t != qi) {
      // ---- non-diagonal tile: raw max + upper bound, fused bias+exp2 ----
      float rmax = -3.0e38f;
#pragma unroll
      for (int nf = 0; nf < 4; ++nf)
#pragma unroll
        for (int r = 0; r < 4; ++r) rmax = fmaxf(rmax, tt[nf][r]);
      rmax = fmaxf(rmax, __shfl_xor(rmax, 16));
      rmax = fmaxf(rmax, __shfl_xor(rmax, 32));
      const float bound = fmaf(rmax, SCALE, tb + sl2 * 63.f);  // >= true biased row max
      if (!__all(bound <= m + 12.0f)) {
        const float mnew = fmaxf(m, bound);
        const float corr = __builtin_amdgcn_exp2f(m - mnew);
        m = mnew;
#pragma unroll
        for (int nf = 0; nf < 4; ++nf) oT[nf] *= corr;
        oX *= corr;
      }
      const float tbm = tb - m;
#pragma unroll
      for (int nf = 0; nf < 4; ++nf) {
        const f32x4 bb = base[nf] + tbm;
#pragma unroll
        for (int r = 0; r < 4; ++r)
          tt[nf][r] = __builtin_amdgcn_exp2f(fmaf(tt[nf][r], SCALE, bb[r]));
      }
    } else {
      // ---- diagonal tile: exact per-element bias + causal mask ----
      float rmax = -3.0e38f;
#pragma unroll
      for (int nf = 0; nf < 4; ++nf)
#pragma unroll
        for (int r = 0; r < 4; ++r) {
          float sv = fmaf(tt[nf][r], SCALE, base[nf][r] + tb);
          if (nf * 16 + 4 * g + r > ir0) sv = -3.0e38f;
          tt[nf][r] = sv;
          rmax = fmaxf(rmax, sv);
        }
      rmax = fmaxf(rmax, __shfl_xor(rmax, 16));
      rmax = fmaxf(rmax, __shfl_xor(rmax, 32));
      if (!__all(rmax <= m + 12.0f)) {
        const float mnew = fmaxf(m, rmax);
        const float corr = __builtin_amdgcn_exp2f(m - mnew);
        m = mnew;
#pragma unroll
        for (int nf = 0; nf < 4; ++nf) oT[nf] *= corr;
        oX *= corr;
      }
#pragma unroll
      for (int nf = 0; nf < 4; ++nf)
#pragma unroll
        for (int r = 0; r < 4; ++r) tt[nf][r] = __builtin_amdgcn_exp2f(tt[nf][r] - m);
    }
    // P -> wave-private swizzled sP; wave-internal lgkm ordering, no barrier
    char* pw = reinterpret_cast<char*>(sP[wave]);
#pragma unroll
    for (int nf = 0; nf < 4; ++nf) {
      bfx4 w = {(__bf16)tt[nf][0], (__bf16)tt[nf][1], (__bf16)tt[nf][2], (__bf16)tt[nf][3]};
      *reinterpret_cast<bfx4*>(pw + swz128((q << 7) + nf * 32 + g * 8)) = w;
    }
    bfx8 pa[2];
#pragma unroll
    for (int kc = 0; kc < 2; ++kc)
      pa[kc] = *reinterpret_cast<const bfx8*>(pw + swz128((q << 7) + kc * 64 + (g << 4)));
    __builtin_amdgcn_s_setprio(1);
#pragma unroll
    for (int kc = 0; kc < 2; ++kc) {
#pragma unroll
      for (int nf = 0; nf < 4; ++nf) {
        const bfx8 vf =
            *reinterpret_cast<const bfx8*>(sVc + swz128(((nf * 16 + q) << 7) + kc * 64 + (g << 4)));
        oT[nf] = __builtin_amdgcn_mfma_f32_16x16x32_bf16(vf, pa[kc], oT[nf], 0, 0, 0);
      }
      oX = __builtin_amdgcn_mfma_f32_16x16x32_bf16(onesf, pa[kc], oX, 0, 0, 0);  // l rides PV
    }
    __builtin_amdgcn_s_setprio(0);
    __syncthreads();
    cur ^= 1;
  }
  if (slot < 0) {
    const float rl = 1.0f / oX[0];
    const int row = w0 + q;
#pragma unroll
    for (int nf = 0; nf < 4; ++nf) {
      bfx4 w = {(__bf16)(oT[nf][0] * rl), (__bf16)(oT[nf][1] * rl), (__bf16)(oT[nf][2] * rl),
                (__bf16)(oT[nf][3] * rl)};
      const int col = h * 64 + nf * 16 + g * 4;
      *reinterpret_cast<bfx4*>(reinterpret_cast<char*>(Y) +
                               (((size_t)b * S_ + row) * E_ + col) * 2) = w;
    }
  } else {
    const int sg = bh * 48 + slot;
    u16* po = pO + (size_t)sg * 4096 + (size_t)(wave * 16 + q) * 64;
#pragma unroll
    for (int nf = 0; nf < 4; ++nf) {
      bfx4 w = {(__bf16)oT[nf][0], (__bf16)oT[nf][1], (__bf16)oT[nf][2], (__bf16)oT[nf][3]};
      *reinterpret_cast<bfx4*>(po + nf * 16 + g * 4) = w;
    }
    if (g == 0) {
      float2 ml = make_float2(m, oX[0]);
      reinterpret_cast<float2*>(pML)[sg * 64 + wave * 16 + q] = ml;
    }
  }
}

// ---------------- merge partial chunks: Y[rows] = sum_c w_c O_c / sum_c w_c l_c ----------------
__global__ __launch_bounds__(256) void merge_attn(const u16* __restrict__ pO,
                                                  const float* __restrict__ pML,
                                                  u16* __restrict__ Y) {
  const int mb = blockIdx.x;
  const int bh = mb / 20, qq = mb % 20, qi = 12 + qq;  // only qi>=12 are split
  const int nch = (qi < 24) ? 2 : 3;
  const int sb = (qi < 24) ? (qi - 12) * 2 : 24 + (qi - 24) * 3;
  const int b = bh >> 4, h = bh & 15;
  const int tid = threadIdx.x;
  const int r = tid >> 2, dq = (tid & 3) * 16;
  const float2* ml2 = reinterpret_cast<const float2*>(pML);
  float mm[3], ll[3];
  float M = -3.0e38f;
#pragma unroll
  for (int c = 0; c < 3; ++c) {
    if (c < nch) {
      const float2 v = ml2[(bh * 48 + sb + c) * 64 + r];
      mm[c] = v.x;
      ll[c] = v.y;
      M = fmaxf(M, v.x);
    } else {
      mm[c] = -3.0e38f;
      ll[c] = 0.f;
    }
  }
  float L = 0.f, acc[16];
#pragma unroll
  for (int i = 0; i < 16; ++i) acc[i] = 0.f;
#pragma unroll
  for (int c = 0; c < 3; ++c) {
    if (c < nch) {
      const float w = __builtin_amdgcn_exp2f(mm[c] - M);
      L += w * ll[c];
      const u16* src = pO + (size_t)(bh * 48 + sb + c) * 4096 + r * 64 + dq;
      const u16x8 a = *reinterpret_cast<const u16x8*>(src);
      const u16x8 bb = *reinterpret_cast<const u16x8*>(src + 8);
#pragma unroll
      for (int i = 0; i < 8; ++i) {
        acc[i] += w * __uint_as_float(((unsigned)a[i]) << 16);
        acc[8 + i] += w * __uint_as_float(((unsigned)bb[i]) << 16);
      }
    }
  }
  const float rl = 1.0f / L;
  u16x8 o0, o1;
#pragma unroll
  for (int i = 0; i < 8; ++i) {
    o0[i] = f2bf(acc[i] * rl);
    o1[i] = f2bf(acc[8 + i] * rl);
  }
  u16* dst = Y + ((size_t)b * S_ + qi * 64 + r) * E_ + h * 64 + dq;
  *reinterpret_cast<u16x8*>(dst) = o0;
  *reinterpret_cast<u16x8*>(dst + 8) = o1;
}

extern "C" void kernel_launch(void* const* d_in, const int* in_sizes, int n_in, void* d_out,
                              int out_size, void* d_ws, size_t ws_size, hipStream_t stream) {
  (void)in_sizes; (void)n_in; (void)out_size; (void)ws_size;
  const float* x = (const float*)d_in[0];
  const float* Wkqv = (const float*)d_in[1];
  const float* bkqv = (const float*)d_in[2];
  const float* Wproj = (const float*)d_in[3];
  const float* bproj = (const float*)d_in[4];
  const float* slopes = (const float*)d_in[5];
  float* out = (float*)d_out;

  const size_t MBE = (size_t)4096 * 1024;
  u16* xb = (u16*)d_ws;                       // x bf16              [4096][1024]
  u16* wkqvt = xb + MBE;                      // W_kqv^T bf16        [3072][1024]
  u16* wprojt = wkqvt + (size_t)3072 * 1024;  // W_proj^T bf16       [1024][1024]
  u16* kbuf = wprojt + (size_t)1024 * 1024;   // K   [B][H][S][D]
  u16* qbuf = kbuf + MBE;                     // Q   [B][H][S][D]
  u16* vtbuf = qbuf + MBE;                    // V^T [B][H][D][S]
  u16* ybuf = vtbuf + MBE;                    // attn out [B][S][E]
  // partial-chunk scratch overlays xb+wkqvt (dead after gemm_kqv): 12.6 MB O + 0.79 MB ml
  u16* pO = xb;                                      // [1536][64][64] bf16
  float* pML = (float*)(xb + (size_t)1536 * 4096);   // [1536][64][2] f32

  prep<<<dim3(3072), dim3(256), 0, stream>>>(x, Wkqv, Wproj, xb, wkqvt, wprojt);
  gemm_kqv<<<dim3(24, 32), dim3(512), 0, stream>>>(xb, wkqvt, bkqv, 4096, 3072, 1024, kbuf, qbuf,
                                                   vtbuf);
  attn_alibi<<<dim3(1920), dim3(256), 0, stream>>>(qbuf, kbuf, vtbuf, slopes, ybuf, pO, pML);
  merge_attn<<<dim3(640), dim3(256), 0, stream>>>(pO, pML, ybuf);
  gemm_proj<<<dim3(8, 32), dim3(512), 0, stream>>>(ybuf, wprojt, bproj, 4096, 1024, 1024, out);
}

// Round 14
// 122.514 us; speedup vs baseline: 1.0036x; 1.0036x over previous
//
#include <hip/hip_runtime.h>

typedef unsigned short u16;
typedef float f32x4 __attribute__((ext_vector_type(4)));
typedef __bf16 bfx8 __attribute__((ext_vector_type(8)));
typedef __bf16 bfx4 __attribute__((ext_vector_type(4)));
typedef u16 u16x8 __attribute__((ext_vector_type(8)));
typedef u16 u16x4 __attribute__((ext_vector_type(4)));

#define B_ 2
#define S_ 2048
#define E_ 1024
#define H_ 16
#define D_ 64

__device__ __forceinline__ u16 f2bf(float f) {
  unsigned u = __float_as_uint(f);
  u = u + 0x7FFFu + ((u >> 16) & 1u);  // RNE
  return (u16)(u >> 16);
}

// XOR swizzle for tiles with 128B rows: byte ^= ((row&7)<<4).
__device__ __forceinline__ int swz128(int o) { return o ^ ((o >> 3) & 0x70); }

// async global->LDS, 16B per lane; LDS dest is wave-uniform base (HW adds lane*16).
__device__ __forceinline__ void gload16(const void* g, void* l) {
  __builtin_amdgcn_global_load_lds((const __attribute__((address_space(1))) void*)g,
                                   (__attribute__((address_space(3))) void*)l, 16, 0, 0);
}

// Chunk table: 60 work items per (bh): (qi, t0, t1, slot), ordered ~longest-first.
// slot >= 0 -> partial chunk (needs merge); slot < 0 -> sole chunk, writes Y directly.
__device__ const signed char TQI[60] = {31, 31, 30, 30, 29, 29, 28, 28, 27, 27, 26, 26, 25, 25, 24,
                                        24, 23, 23, 22, 21, 20, 19, 18, 17, 16, 15, 14, 13, 12, 11,
                                        22, 10, 21, 9,  20, 8,  31, 19, 7,  30, 18, 6,  29, 17, 5,
                                        28, 16, 4,  27, 15, 3,  26, 14, 2,  25, 13, 1,  24, 12, 0};
__device__ const signed char TT0[60] = {0,  12, 0,  12, 0,  12, 0,  12, 0,  12, 0,  12, 0,  12, 0,
                                        12, 0,  12, 0,  0,  0,  0,  0,  0,  0,  0,  0,  0,  0,  0,
                                        12, 0,  12, 0,  12, 0,  24, 12, 0,  24, 12, 0,  24, 12, 0,
                                        24, 12, 0,  24, 12, 0,  24, 12, 0,  24, 12, 0,  24, 12, 0};
__device__ const signed char TT1[60] = {12, 24, 12, 24, 12, 24, 12, 24, 12, 24, 12, 24, 12, 24, 12,
                                        24, 12, 24, 12, 12, 12, 12, 12, 12, 12, 12, 12, 12, 12, 12,
                                        23, 11, 22, 10, 21, 9,  32, 20, 8,  31, 19, 7,  30, 18, 6,
                                        29, 17, 5,  28, 16, 4,  27, 15, 3,  26, 14, 2,  25, 13, 1};
__device__ const signed char TSL[60] = {45, 46, 42, 43, 39, 40, 36, 37, 33, 34, 30, 31, 27, 28, 24,
                                        25, 22, 23, 20, 18, 16, 14, 12, 10, 8,  6,  4,  2,  0,  -1,
                                        21, -1, 19, -1, 17, -1, 47, 15, -1, 44, 13, -1, 41, 11, -1,
                                        38, 9,  -1, 35, 7,  -1, 32, 5,  -1, 29, 3,  -1, 26, 1,  -1};

// ---------------- fused prep: x->bf16 convert + W_kqv^T + W_proj^T (bf16) ----------------
__global__ __launch_bounds__(256) void prep(const float* __restrict__ x,
                                            const float* __restrict__ Wk,
                                            const float* __restrict__ Wp, u16* __restrict__ xb,
                                            u16* __restrict__ wkt, u16* __restrict__ wpt) {
  __shared__ float tile[64][65];
  const int id = blockIdx.x, tid = threadIdx.x;
  if (id < 2048) {  // convert x: 2^20 float4 elements
    const float4* in4 = reinterpret_cast<const float4*>(x);
    u16x4* out4 = reinterpret_cast<u16x4*>(xb);
    int i = id * 256 + tid;
#pragma unroll
    for (int p = 0; p < 2; ++p, i += 524288) {
      const float4 v = in4[i];
      u16x4 o = {f2bf(v.x), f2bf(v.y), f2bf(v.z), f2bf(v.w)};
      out4[i] = o;
    }
    return;
  }
  const float* in;
  u16* out;
  int R, C, bx, by;
  if (id < 2816) {
    const int t = id - 2048;
    in = Wk; out = wkt; R = 1024; C = 3072; bx = t % 48; by = t / 48;
  } else {
    const int t = id - 2816;
    in = Wp; out = wpt; R = 1024; C = 1024; bx = t & 15; by = t >> 4;
  }
  const int ct = bx * 64, rt = by * 64;
#pragma unroll
  for (int p = 0; p < 4; ++p) {
    int f = p * 256 + tid;
    int row = f >> 4, c4 = (f & 15) << 2;
    const float4 v = *reinterpret_cast<const float4*>(in + (size_t)(rt + row) * C + ct + c4);
    tile[row][c4 + 0] = v.x; tile[row][c4 + 1] = v.y;
    tile[row][c4 + 2] = v.z; tile[row][c4 + 3] = v.w;
  }
  __syncthreads();
#pragma unroll
  for (int p = 0; p < 4; ++p) {
    int g = p * 256 + tid;
    int orow = g >> 4, k4 = (g & 15) << 2;
    u16x4 o = {f2bf(tile[k4 + 0][orow]), f2bf(tile[k4 + 1][orow]),
               f2bf(tile[k4 + 2][orow]), f2bf(tile[k4 + 3][orow])};
    *reinterpret_cast<u16x4*>(out + (size_t)(ct + orow) * R + rt + k4) = o;
  }
}

// ---------------- bf16 GEMM kqv (8 waves, 512 thr, dbuf): C = A @ Bt^T + bias ----------------
// Wave grid 4x2 (wr rows x wc cols): each wave owns 32 rows x 64 cols, so its nf-sweep
// completes FULL 128B output rows (one head's D=64) -> write-combining holds (R13 lesson:
// 32-col waves caused +24MB write-allocate FETCH). K-loop: validated dbuf structure.
// Epilogue: R9/R12-verbatim per-element scatter pattern.
__global__ __launch_bounds__(512) void gemm_kqv(const u16* __restrict__ A,
                                                const u16* __restrict__ Bt,
                                                const float* __restrict__ bias, int M, int N, int K,
                                                u16* __restrict__ outK, u16* __restrict__ outQ,
                                                u16* __restrict__ outVt) {
  __shared__ __align__(16) u16 sA[2][8192];
  __shared__ __align__(16) u16 sB[2][8192];
  const int tid = threadIdx.x, lane = tid & 63;
  const int wave = tid >> 6, wr = wave >> 1, wc = wave & 1;  // 4x2 waves of 32x64
  int lin = blockIdx.y * gridDim.x + blockIdx.x;
  const int nwg = gridDim.x * gridDim.y;
  if ((nwg & 7) == 0) {  // bijective XCD-chunked swizzle
    const int cpx = nwg >> 3;
    lin = (lin & 7) * cpx + (lin >> 3);
  }
  const int bm = (lin / gridDim.x) * 128, bn = (lin % gridDim.x) * 128;
  const int r8 = lane >> 3, c16 = (lane & 7) ^ r8;
  f32x4 acc[2][4] = {};

  auto stage = [&](int k0, int buf) {
#pragma unroll
    for (int i = 0; i < 2; ++i) {
      const int c = wave * 2 + i;  // 16 chunks of 1KB
      const int row = c * 8 + r8;
      gload16(A + (size_t)(bm + row) * K + k0 + c16 * 8, (char*)sA[buf] + c * 1024);
      gload16(Bt + (size_t)(bn + row) * K + k0 + c16 * 8, (char*)sB[buf] + c * 1024);
    }
  };

  stage(0, 0);
  __syncthreads();
  int cur = 0;
  for (int k0 = 0; k0 < K; k0 += 64) {
    if (k0 + 64 < K) stage(k0 + 64, cur ^ 1);  // in flight across compute; drained at barrier
#pragma unroll
    for (int kc = 0; kc < 2; ++kc) {
      bfx8 af[2], bf[4];
#pragma unroll
      for (int mf = 0; mf < 2; ++mf) {
        int o = swz128(((wr * 32 + mf * 16 + (lane & 15)) << 7) + kc * 64 + ((lane >> 4) << 4));
        af[mf] = *reinterpret_cast<const bfx8*>(reinterpret_cast<const char*>(sA[cur]) + o);
      }
#pragma unroll
      for (int nf = 0; nf < 4; ++nf) {
        int o = swz128(((wc * 64 + nf * 16 + (lane & 15)) << 7) + kc * 64 + ((lane >> 4) << 4));
        bf[nf] = *reinterpret_cast<const bfx8*>(reinterpret_cast<const char*>(sB[cur]) + o);
      }
#pragma unroll
      for (int mf = 0; mf < 2; ++mf)
#pragma unroll
        for (int nf = 0; nf < 4; ++nf)
          acc[mf][nf] = __builtin_amdgcn_mfma_f32_16x16x32_bf16(af[mf], bf[nf], acc[mf][nf], 0, 0, 0);
    }
    __syncthreads();
    cur ^= 1;
  }
#pragma unroll
  for (int mf = 0; mf < 2; ++mf)
#pragma unroll
    for (int nf = 0; nf < 4; ++nf)
#pragma unroll
      for (int r = 0; r < 4; ++r) {
        const int row = bm + wr * 32 + mf * 16 + ((lane >> 4) << 2) + r;
        const int col = bn + wc * 64 + nf * 16 + (lane & 15);
        const float v = acc[mf][nf][r] + bias[col];
        const int chunk = col >> 10, w = col & 1023, h = w >> 6, dd = w & 63;
        const int b = row >> 11, s = row & 2047;
        const int bh = b * H_ + h;
        if (chunk == 0)
          outK[((size_t)bh * S_ + s) * D_ + dd] = f2bf(v);
        else if (chunk == 1)
          outQ[((size_t)bh * S_ + s) * D_ + dd] = f2bf(v);
        else
          outVt[((size_t)bh * D_ + dd) * S_ + s] = f2bf(v);  // fused V transpose
      }
}

// ---------------- proj GEMM (8 waves, 512 thr): fp32 out row-major ----------------
// Double-buffered global_load_lds staging (stage t+1 before compute t, one barrier/iter):
// at 1 block/CU there is no cross-block TLP, so prefetch must hide the load latency.
__global__ __launch_bounds__(512) void gemm_proj(const u16* __restrict__ A,
                                                 const u16* __restrict__ Bt,
                                                 const float* __restrict__ bias, int M, int N,
                                                 int K, float* __restrict__ outF) {
  __shared__ __align__(16) u16 sA[2][8192];
  __shared__ __align__(16) u16 sB[2][8192];
  const int tid = threadIdx.x, lane = tid & 63;
  const int wave = tid >> 6, wr = wave >> 2, wc = wave & 3;  // 2x4 waves of 64x32
  int lin = blockIdx.y * gridDim.x + blockIdx.x;
  const int nwg = gridDim.x * gridDim.y;
  if ((nwg & 7) == 0) {
    const int cpx = nwg >> 3;
    lin = (lin & 7) * cpx + (lin >> 3);
  }
  const int bm = (lin / gridDim.x) * 128, bn = (lin % gridDim.x) * 128;
  const int r8 = lane >> 3, c16 = (lane & 7) ^ r8;
  f32x4 acc[4][2] = {};

  auto stage = [&](int k0, int buf) {
#pragma unroll
    for (int i = 0; i < 2; ++i) {
      const int c = wave * 2 + i;  // 16 chunks of 1KB
      const int row = c * 8 + r8;
      gload16(A + (size_t)(bm + row) * K + k0 + c16 * 8, (char*)sA[buf] + c * 1024);
      gload16(Bt + (size_t)(bn + row) * K + k0 + c16 * 8, (char*)sB[buf] + c * 1024);
    }
  };

  stage(0, 0);
  __syncthreads();
  int cur = 0;
  for (int k0 = 0; k0 < K; k0 += 64) {
    if (k0 + 64 < K) stage(k0 + 64, cur ^ 1);  // in flight across compute; drained at barrier
#pragma unroll
    for (int kc = 0; kc < 2; ++kc) {
      bfx8 af[4], bf[2];
#pragma unroll
      for (int mf = 0; mf < 4; ++mf) {
        int o = swz128(((wr * 64 + mf * 16 + (lane & 15)) << 7) + kc * 64 + ((lane >> 4) << 4));
        af[mf] = *reinterpret_cast<const bfx8*>(reinterpret_cast<const char*>(sA[cur]) + o);
      }
#pragma unroll
      for (int nf = 0; nf < 2; ++nf) {
        int o = swz128(((wc * 32 + nf * 16 + (lane & 15)) << 7) + kc * 64 + ((lane >> 4) << 4));
        bf[nf] = *reinterpret_cast<const bfx8*>(reinterpret_cast<const char*>(sB[cur]) + o);
      }
#pragma unroll
      for (int mf = 0; mf < 4; ++mf)
#pragma unroll
        for (int nf = 0; nf < 2; ++nf)
          acc[mf][nf] = __builtin_amdgcn_mfma_f32_16x16x32_bf16(af[mf], bf[nf], acc[mf][nf], 0, 0, 0);
    }
    __syncthreads();
    cur ^= 1;
  }
#pragma unroll
  for (int mf = 0; mf < 4; ++mf)
#pragma unroll
    for (int nf = 0; nf < 2; ++nf)
#pragma unroll
      for (int r = 0; r < 4; ++r) {
        const int row = bm + wr * 64 + mf * 16 + ((lane >> 4) << 2) + r;
        const int col = bn + wc * 32 + nf * 16 + (lane & 15);
        outF[(size_t)row * N + col] = acc[mf][nf][r] + bias[col];
      }
}

// ---------------- flash attention with ALiBi, causal — split-KV chunked ----------------
// 1920 blocks = 8 XCD x 4 bh x 60 chunks; 4 blocks/CU resident, queue smooths imbalance.
// Sole chunks write Y; split chunks write unnormalized O + (m,l), merged by merge_attn.
__global__ __launch_bounds__(256, 4) void attn_alibi(const u16* __restrict__ Q,
                                                     const u16* __restrict__ Kb,
                                                     const u16* __restrict__ Vt,
                                                     const float* __restrict__ slopes,
                                                     u16* __restrict__ Y, u16* __restrict__ pO,
                                                     float* __restrict__ pML) {
  __shared__ __align__(16) u16 sK[2][4096];
  __shared__ __align__(16) u16 sV[2][4096];
  __shared__ __align__(16) __bf16 sP[4][16 * 64];
  const int id = blockIdx.x;
  const int xcd = id & 7, j = id >> 3;       // id%8 = XCD (round-robin dispatch)
  const int bh = xcd * 4 + (j & 3);          // 4 heads pinned per XCD (L2-resident K/V)
  const int c = j >> 2;                      // 0..59 chunk-table index
  const int qi = TQI[c], t0 = TT0[c], t1 = TT1[c], slot = TSL[c];
  const int b = bh >> 4, h = bh & 15;
  const int tid = threadIdx.x, lane = tid & 63, wave = tid >> 6;
  const int q = lane & 15, g = lane >> 4;
  const int q0 = qi * 64;
  const int w0 = q0 + wave * 16;
  const float L2E = 1.44269504089f;
  const float SCALE = 0.125f * L2E;
  const float sl2 = slopes[h] * L2E;
  const size_t headSD = (size_t)bh * (S_ * D_);
  const size_t headDS = (size_t)bh * (D_ * S_);
  const int r8 = lane >> 3, c16 = (lane & 7) ^ r8;

  bfx8 qf[2];
  {
    const u16* qp = Q + headSD + (size_t)(w0 + q) * D_ + g * 8;
    qf[0] = *reinterpret_cast<const bfx8*>(qp);
    qf[1] = *reinterpret_cast<const bfx8*>(qp + 32);
  }
  bfx8 onesf;
#pragma unroll
  for (int jj = 0; jj < 8; ++jj) onesf[jj] = (__bf16)1.0f;
  f32x4 base[4];
#pragma unroll
  for (int nf = 0; nf < 4; ++nf)
#pragma unroll
    for (int r = 0; r < 4; ++r) base[nf][r] = sl2 * (float)(nf * 16 + 4 * g + r);
  const int ir0 = wave * 16 + q;  // diagonal-tile mask boundary

  float m = 0.f;
  f32x4 oT[4] = {};
  f32x4 oX = {};  // l accumulator (all components equal l)

  auto stage = [&](int t, int buf) {
#pragma unroll
    for (int i = 0; i < 2; ++i) {
      const int cc = wave * 2 + i;
      const int row = cc * 8 + r8;
      gload16(Kb + headSD + (size_t)t * 4096 + row * 64 + c16 * 8, (char*)sK[buf] + cc * 1024);
      gload16(Vt + headDS + (size_t)row * S_ + t * 64 + c16 * 8, (char*)sV[buf] + cc * 1024);
    }
  };

  stage(t0, 0);
  __syncthreads();
  int cur = 0;
  for (int t = t0; t < t1; ++t) {
    if (t + 1 < t1) stage(t + 1, cur ^ 1);
    const char* sKc = reinterpret_cast<const char*>(sK[cur]);
    const char* sVc = reinterpret_cast<const char*>(sV[cur]);
    f32x4 tt[4] = {};
    __builtin_amdgcn_s_setprio(1);
#pragma unroll
    for (int kc = 0; kc < 2; ++kc)
#pragma unroll
      for (int nf = 0; nf < 4; ++nf) {
        const bfx8 kf =
            *reinterpret_cast<const bfx8*>(sKc + swz128(((nf * 16 + q) << 7) + kc * 64 + (g << 4)));
        tt[nf] = __builtin_amdgcn_mfma_f32_16x16x32_bf16(kf, qf[kc], tt[nf], 0, 0, 0);
      }
    __builtin_amdgcn_s_setprio(0);
    const float tb = sl2 * (float)(t * 64);
    if (t != qi) {
      // ---- non-diagonal tile: raw max + upper bound, fused bias+exp2 ----
      float rmax = -3.0e38f;
#pragma unroll
      for (int nf = 0; nf < 4; ++nf)
#pragma unroll
        for (int r = 0; r < 4; ++r) rmax = fmaxf(rmax, tt[nf][r]);
      rmax = fmaxf(rmax, __shfl_xor(rmax, 16));
      rmax = fmaxf(rmax, __shfl_xor(rmax, 32));
      const float bound = fmaf(rmax, SCALE, tb + sl2 * 63.f);  // >= true biased row max
      if (!__all(bound <= m + 12.0f)) {
        const float mnew = fmaxf(m, bound);
        const float corr = __builtin_amdgcn_exp2f(m - mnew);
        m = mnew;
#pragma unroll
        for (int nf = 0; nf < 4; ++nf) oT[nf] *= corr;
        oX *= corr;
      }
      const float tbm = tb - m;
#pragma unroll
      for (int nf = 0; nf < 4; ++nf) {
        const f32x4 bb = base[nf] + tbm;
#pragma unroll
        for (int r = 0; r < 4; ++r)
          tt[nf][r] = __builtin_amdgcn_exp2f(fmaf(tt[nf][r], SCALE, bb[r]));
      }
    } else {
      // ---- diagonal tile: exact per-element bias + causal mask ----
      float rmax = -3.0e38f;
#pragma unroll
      for (int nf = 0; nf < 4; ++nf)
#pragma unroll
        for (int r = 0; r < 4; ++r) {
          float sv = fmaf(tt[nf][r], SCALE, base[nf][r] + tb);
          if (nf * 16 + 4 * g + r > ir0) sv = -3.0e38f;
          tt[nf][r] = sv;
          rmax = fmaxf(rmax, sv);
        }
      rmax = fmaxf(rmax, __shfl_xor(rmax, 16));
      rmax = fmaxf(rmax, __shfl_xor(rmax, 32));
      if (!__all(rmax <= m + 12.0f)) {
        const float mnew = fmaxf(m, rmax);
        const float corr = __builtin_amdgcn_exp2f(m - mnew);
        m = mnew;
#pragma unroll
        for (int nf = 0; nf < 4; ++nf) oT[nf] *= corr;
        oX *= corr;
      }
#pragma unroll
      for (int nf = 0; nf < 4; ++nf)
#pragma unroll
        for (int r = 0; r < 4; ++r) tt[nf][r] = __builtin_amdgcn_exp2f(tt[nf][r] - m);
    }
    // P -> wave-private swizzled sP; wave-internal lgkm ordering, no barrier
    char* pw = reinterpret_cast<char*>(sP[wave]);
#pragma unroll
    for (int nf = 0; nf < 4; ++nf) {
      bfx4 w = {(__bf16)tt[nf][0], (__bf16)tt[nf][1], (__bf16)tt[nf][2], (__bf16)tt[nf][3]};
      *reinterpret_cast<bfx4*>(pw + swz128((q << 7) + nf * 32 + g * 8)) = w;
    }
    bfx8 pa[2];
#pragma unroll
    for (int kc = 0; kc < 2; ++kc)
      pa[kc] = *reinterpret_cast<const bfx8*>(pw + swz128((q << 7) + kc * 64 + (g << 4)));
    __builtin_amdgcn_s_setprio(1);
#pragma unroll
    for (int kc = 0; kc < 2; ++kc) {
#pragma unroll
      for (int nf = 0; nf < 4; ++nf) {
        const bfx8 vf =
            *reinterpret_cast<const bfx8*>(sVc + swz128(((nf * 16 + q) << 7) + kc * 64 + (g << 4)));
        oT[nf] = __builtin_amdgcn_mfma_f32_16x16x32_bf16(vf, pa[kc], oT[nf], 0, 0, 0);
      }
      oX = __builtin_amdgcn_mfma_f32_16x16x32_bf16(onesf, pa[kc], oX, 0, 0, 0);  // l rides PV
    }
    __builtin_amdgcn_s_setprio(0);
    __syncthreads();
    cur ^= 1;
  }
  if (slot < 0) {
    const float rl = 1.0f / oX[0];
    const int row = w0 + q;
#pragma unroll
    for (int nf = 0; nf < 4; ++nf) {
      bfx4 w = {(__bf16)(oT[nf][0] * rl), (__bf16)(oT[nf][1] * rl), (__bf16)(oT[nf][2] * rl),
                (__bf16)(oT[nf][3] * rl)};
      const int col = h * 64 + nf * 16 + g * 4;
      *reinterpret_cast<bfx4*>(reinterpret_cast<char*>(Y) +
                               (((size_t)b * S_ + row) * E_ + col) * 2) = w;
    }
  } else {
    const int sg = bh * 48 + slot;
    u16* po = pO + (size_t)sg * 4096 + (size_t)(wave * 16 + q) * 64;
#pragma unroll
    for (int nf = 0; nf < 4; ++nf) {
      bfx4 w = {(__bf16)oT[nf][0], (__bf16)oT[nf][1], (__bf16)oT[nf][2], (__bf16)oT[nf][3]};
      *reinterpret_cast<bfx4*>(po + nf * 16 + g * 4) = w;
    }
    if (g == 0) {
      float2 ml = make_float2(m, oX[0]);
      reinterpret_cast<float2*>(pML)[sg * 64 + wave * 16 + q] = ml;
    }
  }
}

// ---------------- merge partial chunks: Y[rows] = sum_c w_c O_c / sum_c w_c l_c ----------------
__global__ __launch_bounds__(256) void merge_attn(const u16* __restrict__ pO,
                                                  const float* __restrict__ pML,
                                                  u16* __restrict__ Y) {
  const int mb = blockIdx.x;
  const int bh = mb / 20, qq = mb % 20, qi = 12 + qq;  // only qi>=12 are split
  const int nch = (qi < 24) ? 2 : 3;
  const int sb = (qi < 24) ? (qi - 12) * 2 : 24 + (qi - 24) * 3;
  const int b = bh >> 4, h = bh & 15;
  const int tid = threadIdx.x;
  const int r = tid >> 2, dq = (tid & 3) * 16;
  const float2* ml2 = reinterpret_cast<const float2*>(pML);
  float mm[3], ll[3];
  float M = -3.0e38f;
#pragma unroll
  for (int c = 0; c < 3; ++c) {
    if (c < nch) {
      const float2 v = ml2[(bh * 48 + sb + c) * 64 + r];
      mm[c] = v.x;
      ll[c] = v.y;
      M = fmaxf(M, v.x);
    } else {
      mm[c] = -3.0e38f;
      ll[c] = 0.f;
    }
  }
  float L = 0.f, acc[16];
#pragma unroll
  for (int i = 0; i < 16; ++i) acc[i] = 0.f;
#pragma unroll
  for (int c = 0; c < 3; ++c) {
    if (c < nch) {
      const float w = __builtin_amdgcn_exp2f(mm[c] - M);
      L += w * ll[c];
      const u16* src = pO + (size_t)(bh * 48 + sb + c) * 4096 + r * 64 + dq;
      const u16x8 a = *reinterpret_cast<const u16x8*>(src);
      const u16x8 bb = *reinterpret_cast<const u16x8*>(src + 8);
#pragma unroll
      for (int i = 0; i < 8; ++i) {
        acc[i] += w * __uint_as_float(((unsigned)a[i]) << 16);
        acc[8 + i] += w * __uint_as_float(((unsigned)bb[i]) << 16);
      }
    }
  }
  const float rl = 1.0f / L;
  u16x8 o0, o1;
#pragma unroll
  for (int i = 0; i < 8; ++i) {
    o0[i] = f2bf(acc[i] * rl);
    o1[i] = f2bf(acc[8 + i] * rl);
  }
  u16* dst = Y + ((size_t)b * S_ + qi * 64 + r) * E_ + h * 64 + dq;
  *reinterpret_cast<u16x8*>(dst) = o0;
  *reinterpret_cast<u16x8*>(dst + 8) = o1;
}

extern "C" void kernel_launch(void* const* d_in, const int* in_sizes, int n_in, void* d_out,
                              int out_size, void* d_ws, size_t ws_size, hipStream_t stream) {
  (void)in_sizes; (void)n_in; (void)out_size; (void)ws_size;
  const float* x = (const float*)d_in[0];
  const float* Wkqv = (const float*)d_in[1];
  const float* bkqv = (const float*)d_in[2];
  const float* Wproj = (const float*)d_in[3];
  const float* bproj = (const float*)d_in[4];
  const float* slopes = (const float*)d_in[5];
  float* out = (float*)d_out;

  const size_t MBE = (size_t)4096 * 1024;
  u16* xb = (u16*)d_ws;                       // x bf16              [4096][1024]
  u16* wkqvt = xb + MBE;                      // W_kqv^T bf16        [3072][1024]
  u16* wprojt = wkqvt + (size_t)3072 * 1024;  // W_proj^T bf16       [1024][1024]
  u16* kbuf = wprojt + (size_t)1024 * 1024;   // K   [B][H][S][D]
  u16* qbuf = kbuf + MBE;                     // Q   [B][H][S][D]
  u16* vtbuf = qbuf + MBE;                    // V^T [B][H][D][S]
  u16* ybuf = vtbuf + MBE;                    // attn out [B][S][E]
  // partial-chunk scratch overlays xb+wkqvt (dead after gemm_kqv): 12.6 MB O + 0.79 MB ml
  u16* pO = xb;                                      // [1536][64][64] bf16
  float* pML = (float*)(xb + (size_t)1536 * 4096);   // [1536][64][2] f32

  prep<<<dim3(3072), dim3(256), 0, stream>>>(x, Wkqv, Wproj, xb, wkqvt, wprojt);
  gemm_kqv<<<dim3(24, 32), dim3(512), 0, stream>>>(xb, wkqvt, bkqv, 4096, 3072, 1024, kbuf, qbuf,
                                                   vtbuf);
  attn_alibi<<<dim3(1920), dim3(256), 0, stream>>>(qbuf, kbuf, vtbuf, slopes, ybuf, pO, pML);
  merge_attn<<<dim3(640), dim3(256), 0, stream>>>(pO, pML, ybuf);
  gemm_proj<<<dim3(8, 32), dim3(512), 0, stream>>>(ybuf, wprojt, bproj, 4096, 1024, 1024, out);
}

// Round 15
// 113.898 us; speedup vs baseline: 1.0795x; 1.0756x over previous
//
#include <hip/hip_runtime.h>

typedef unsigned short u16;
typedef float f32x4 __attribute__((ext_vector_type(4)));
typedef __bf16 bfx8 __attribute__((ext_vector_type(8)));
typedef __bf16 bfx4 __attribute__((ext_vector_type(4)));
typedef u16 u16x8 __attribute__((ext_vector_type(8)));
typedef u16 u16x4 __attribute__((ext_vector_type(4)));

#define B_ 2
#define S_ 2048
#define E_ 1024
#define H_ 16
#define D_ 64

__device__ __forceinline__ u16 f2bf(float f) {
  unsigned u = __float_as_uint(f);
  u = u + 0x7FFFu + ((u >> 16) & 1u);  // RNE
  return (u16)(u >> 16);
}

// XOR swizzle for tiles with 128B rows: byte ^= ((row&7)<<4).
__device__ __forceinline__ int swz128(int o) { return o ^ ((o >> 3) & 0x70); }

// async global->LDS, 16B per lane; LDS dest is wave-uniform base (HW adds lane*16).
__device__ __forceinline__ void gload16(const void* g, void* l) {
  __builtin_amdgcn_global_load_lds((const __attribute__((address_space(1))) void*)g,
                                   (__attribute__((address_space(3))) void*)l, 16, 0, 0);
}

// Chunk table: 60 work items per (bh): (qi, t0, t1, slot), ordered ~longest-first.
// slot >= 0 -> partial chunk (needs merge); slot < 0 -> sole chunk, writes Y directly.
__device__ const signed char TQI[60] = {31, 31, 30, 30, 29, 29, 28, 28, 27, 27, 26, 26, 25, 25, 24,
                                        24, 23, 23, 22, 21, 20, 19, 18, 17, 16, 15, 14, 13, 12, 11,
                                        22, 10, 21, 9,  20, 8,  31, 19, 7,  30, 18, 6,  29, 17, 5,
                                        28, 16, 4,  27, 15, 3,  26, 14, 2,  25, 13, 1,  24, 12, 0};
__device__ const signed char TT0[60] = {0,  12, 0,  12, 0,  12, 0,  12, 0,  12, 0,  12, 0,  12, 0,
                                        12, 0,  12, 0,  0,  0,  0,  0,  0,  0,  0,  0,  0,  0,  0,
                                        12, 0,  12, 0,  12, 0,  24, 12, 0,  24, 12, 0,  24, 12, 0,
                                        24, 12, 0,  24, 12, 0,  24, 12, 0,  24, 12, 0,  24, 12, 0};
__device__ const signed char TT1[60] = {12, 24, 12, 24, 12, 24, 12, 24, 12, 24, 12, 24, 12, 24, 12,
                                        24, 12, 24, 12, 12, 12, 12, 12, 12, 12, 12, 12, 12, 12, 12,
                                        23, 11, 22, 10, 21, 9,  32, 20, 8,  31, 19, 7,  30, 18, 6,
                                        29, 17, 5,  28, 16, 4,  27, 15, 3,  26, 14, 2,  25, 13, 1};
__device__ const signed char TSL[60] = {45, 46, 42, 43, 39, 40, 36, 37, 33, 34, 30, 31, 27, 28, 24,
                                        25, 22, 23, 20, 18, 16, 14, 12, 10, 8,  6,  4,  2,  0,  -1,
                                        21, -1, 19, -1, 17, -1, 47, 15, -1, 44, 13, -1, 41, 11, -1,
                                        38, 9,  -1, 35, 7,  -1, 32, 5,  -1, 29, 3,  -1, 26, 1,  -1};

// ---------------- fused prep: x->bf16 convert + W_kqv^T + W_proj^T (bf16) ----------------
__global__ __launch_bounds__(256) void prep(const float* __restrict__ x,
                                            const float* __restrict__ Wk,
                                            const float* __restrict__ Wp, u16* __restrict__ xb,
                                            u16* __restrict__ wkt, u16* __restrict__ wpt) {
  __shared__ float tile[64][65];
  const int id = blockIdx.x, tid = threadIdx.x;
  if (id < 2048) {  // convert x: 2^20 float4 elements
    const float4* in4 = reinterpret_cast<const float4*>(x);
    u16x4* out4 = reinterpret_cast<u16x4*>(xb);
    int i = id * 256 + tid;
#pragma unroll
    for (int p = 0; p < 2; ++p, i += 524288) {
      const float4 v = in4[i];
      u16x4 o = {f2bf(v.x), f2bf(v.y), f2bf(v.z), f2bf(v.w)};
      out4[i] = o;
    }
    return;
  }
  const float* in;
  u16* out;
  int R, C, bx, by;
  if (id < 2816) {
    const int t = id - 2048;
    in = Wk; out = wkt; R = 1024; C = 3072; bx = t % 48; by = t / 48;
  } else {
    const int t = id - 2816;
    in = Wp; out = wpt; R = 1024; C = 1024; bx = t & 15; by = t >> 4;
  }
  const int ct = bx * 64, rt = by * 64;
#pragma unroll
  for (int p = 0; p < 4; ++p) {
    int f = p * 256 + tid;
    int row = f >> 4, c4 = (f & 15) << 2;
    const float4 v = *reinterpret_cast<const float4*>(in + (size_t)(rt + row) * C + ct + c4);
    tile[row][c4 + 0] = v.x; tile[row][c4 + 1] = v.y;
    tile[row][c4 + 2] = v.z; tile[row][c4 + 3] = v.w;
  }
  __syncthreads();
#pragma unroll
  for (int p = 0; p < 4; ++p) {
    int g = p * 256 + tid;
    int orow = g >> 4, k4 = (g & 15) << 2;
    u16x4 o = {f2bf(tile[k4 + 0][orow]), f2bf(tile[k4 + 1][orow]),
               f2bf(tile[k4 + 2][orow]), f2bf(tile[k4 + 3][orow])};
    *reinterpret_cast<u16x4*>(out + (size_t)(ct + orow) * R + rt + k4) = o;
  }
}

// ---------------- bf16 GEMM (4 waves): C = A @ Bt^T + bias; EPI0 scatters K/Q/V^T ----------------
// EXACT R9/R12 kernel (44.3 us, 84 VGPR, FETCH 30 MB): per-element chunk branch in the epilogue.
// Do not restructure the store loops or the K-loop -- R10/R11/R13/R14 all regressed it
// (+24 MB write-allocate FETCH or lost occupancy; dbuf adds nothing at ~2 blocks/CU TLP).
__global__ __launch_bounds__(256) void gemm_kqv(const u16* __restrict__ A,
                                                const u16* __restrict__ Bt,
                                                const float* __restrict__ bias, int M, int N, int K,
                                                u16* __restrict__ outK, u16* __restrict__ outQ,
                                                u16* __restrict__ outVt) {
  __shared__ __align__(16) u16 sA[128 * 64];
  __shared__ __align__(16) u16 sB[128 * 64];
  const int tid = threadIdx.x, lane = tid & 63;
  const int wave = tid >> 6, wr = wave >> 1, wc = wave & 1;
  int lin = blockIdx.y * gridDim.x + blockIdx.x;
  const int nwg = gridDim.x * gridDim.y;
  if ((nwg & 7) == 0) {  // bijective XCD-chunked swizzle
    const int cpx = nwg >> 3;
    lin = (lin & 7) * cpx + (lin >> 3);
  }
  const int bm = (lin / gridDim.x) * 128, bn = (lin % gridDim.x) * 128;
  const int r8 = lane >> 3, c16 = (lane & 7) ^ r8;
  f32x4 acc[4][4] = {};
  for (int k0 = 0; k0 < K; k0 += 64) {
#pragma unroll
    for (int i = 0; i < 4; ++i) {
      const int c = wave * 4 + i;
      const int row = c * 8 + r8;
      gload16(A + (size_t)(bm + row) * K + k0 + c16 * 8, (char*)sA + c * 1024);
      gload16(Bt + (size_t)(bn + row) * K + k0 + c16 * 8, (char*)sB + c * 1024);
    }
    __syncthreads();
#pragma unroll
    for (int kc = 0; kc < 2; ++kc) {
      bfx8 af[4], bf[4];
#pragma unroll
      for (int mf = 0; mf < 4; ++mf) {
        int o = swz128(((wr * 64 + mf * 16 + (lane & 15)) << 7) + kc * 64 + ((lane >> 4) << 4));
        af[mf] = *reinterpret_cast<const bfx8*>(reinterpret_cast<const char*>(sA) + o);
      }
#pragma unroll
      for (int nf = 0; nf < 4; ++nf) {
        int o = swz128(((wc * 64 + nf * 16 + (lane & 15)) << 7) + kc * 64 + ((lane >> 4) << 4));
        bf[nf] = *reinterpret_cast<const bfx8*>(reinterpret_cast<const char*>(sB) + o);
      }
#pragma unroll
      for (int mf = 0; mf < 4; ++mf)
#pragma unroll
        for (int nf = 0; nf < 4; ++nf)
          acc[mf][nf] = __builtin_amdgcn_mfma_f32_16x16x32_bf16(af[mf], bf[nf], acc[mf][nf], 0, 0, 0);
    }
    __syncthreads();
  }
#pragma unroll
  for (int mf = 0; mf < 4; ++mf)
#pragma unroll
    for (int nf = 0; nf < 4; ++nf)
#pragma unroll
      for (int r = 0; r < 4; ++r) {
        const int row = bm + wr * 64 + mf * 16 + ((lane >> 4) << 2) + r;
        const int col = bn + wc * 64 + nf * 16 + (lane & 15);
        const float v = acc[mf][nf][r] + bias[col];
        const int chunk = col >> 10, w = col & 1023, h = w >> 6, dd = w & 63;
        const int b = row >> 11, s = row & 2047;
        const int bh = b * H_ + h;
        if (chunk == 0)
          outK[((size_t)bh * S_ + s) * D_ + dd] = f2bf(v);
        else if (chunk == 1)
          outQ[((size_t)bh * S_ + s) * D_ + dd] = f2bf(v);
        else
          outVt[((size_t)bh * D_ + dd) * S_ + s] = f2bf(v);  // fused V transpose
      }
}

// ---------------- proj GEMM (8 waves, 512 thr): fp32 out row-major ----------------
// Double-buffered global_load_lds staging (stage t+1 before compute t, one barrier/iter):
// at 1 block/CU there is no cross-block TLP, so prefetch must hide the load latency.
__global__ __launch_bounds__(512) void gemm_proj(const u16* __restrict__ A,
                                                 const u16* __restrict__ Bt,
                                                 const float* __restrict__ bias, int M, int N,
                                                 int K, float* __restrict__ outF) {
  __shared__ __align__(16) u16 sA[2][8192];
  __shared__ __align__(16) u16 sB[2][8192];
  const int tid = threadIdx.x, lane = tid & 63;
  const int wave = tid >> 6, wr = wave >> 2, wc = wave & 3;  // 2x4 waves of 64x32
  int lin = blockIdx.y * gridDim.x + blockIdx.x;
  const int nwg = gridDim.x * gridDim.y;
  if ((nwg & 7) == 0) {
    const int cpx = nwg >> 3;
    lin = (lin & 7) * cpx + (lin >> 3);
  }
  const int bm = (lin / gridDim.x) * 128, bn = (lin % gridDim.x) * 128;
  const int r8 = lane >> 3, c16 = (lane & 7) ^ r8;
  f32x4 acc[4][2] = {};

  auto stage = [&](int k0, int buf) {
#pragma unroll
    for (int i = 0; i < 2; ++i) {
      const int c = wave * 2 + i;  // 16 chunks of 1KB
      const int row = c * 8 + r8;
      gload16(A + (size_t)(bm + row) * K + k0 + c16 * 8, (char*)sA[buf] + c * 1024);
      gload16(Bt + (size_t)(bn + row) * K + k0 + c16 * 8, (char*)sB[buf] + c * 1024);
    }
  };

  stage(0, 0);
  __syncthreads();
  int cur = 0;
  for (int k0 = 0; k0 < K; k0 += 64) {
    if (k0 + 64 < K) stage(k0 + 64, cur ^ 1);  // in flight across compute; drained at barrier
#pragma unroll
    for (int kc = 0; kc < 2; ++kc) {
      bfx8 af[4], bf[2];
#pragma unroll
      for (int mf = 0; mf < 4; ++mf) {
        int o = swz128(((wr * 64 + mf * 16 + (lane & 15)) << 7) + kc * 64 + ((lane >> 4) << 4));
        af[mf] = *reinterpret_cast<const bfx8*>(reinterpret_cast<const char*>(sA[cur]) + o);
      }
#pragma unroll
      for (int nf = 0; nf < 2; ++nf) {
        int o = swz128(((wc * 32 + nf * 16 + (lane & 15)) << 7) + kc * 64 + ((lane >> 4) << 4));
        bf[nf] = *reinterpret_cast<const bfx8*>(reinterpret_cast<const char*>(sB[cur]) + o);
      }
#pragma unroll
      for (int mf = 0; mf < 4; ++mf)
#pragma unroll
        for (int nf = 0; nf < 2; ++nf)
          acc[mf][nf] = __builtin_amdgcn_mfma_f32_16x16x32_bf16(af[mf], bf[nf], acc[mf][nf], 0, 0, 0);
    }
    __syncthreads();
    cur ^= 1;
  }
#pragma unroll
  for (int mf = 0; mf < 4; ++mf)
#pragma unroll
    for (int nf = 0; nf < 2; ++nf)
#pragma unroll
      for (int r = 0; r < 4; ++r) {
        const int row = bm + wr * 64 + mf * 16 + ((lane >> 4) << 2) + r;
        const int col = bn + wc * 32 + nf * 16 + (lane & 15);
        outF[(size_t)row * N + col] = acc[mf][nf][r] + bias[col];
      }
}

// ---------------- flash attention with ALiBi, causal — split-KV chunked ----------------
// 1920 blocks = 8 XCD x 4 bh x 60 chunks; 4 blocks/CU resident, queue smooths imbalance.
// Sole chunks write Y; split chunks write unnormalized O + (m,l), merged by merge_attn.
__global__ __launch_bounds__(256, 4) void attn_alibi(const u16* __restrict__ Q,
                                                     const u16* __restrict__ Kb,
                                                     const u16* __restrict__ Vt,
                                                     const float* __restrict__ slopes,
                                                     u16* __restrict__ Y, u16* __restrict__ pO,
                                                     float* __restrict__ pML) {
  __shared__ __align__(16) u16 sK[2][4096];
  __shared__ __align__(16) u16 sV[2][4096];
  __shared__ __align__(16) __bf16 sP[4][16 * 64];
  const int id = blockIdx.x;
  const int xcd = id & 7, j = id >> 3;       // id%8 = XCD (round-robin dispatch)
  const int bh = xcd * 4 + (j & 3);          // 4 heads pinned per XCD (L2-resident K/V)
  const int c = j >> 2;                      // 0..59 chunk-table index
  const int qi = TQI[c], t0 = TT0[c], t1 = TT1[c], slot = TSL[c];
  const int b = bh >> 4, h = bh & 15;
  const int tid = threadIdx.x, lane = tid & 63, wave = tid >> 6;
  const int q = lane & 15, g = lane >> 4;
  const int q0 = qi * 64;
  const int w0 = q0 + wave * 16;
  const float L2E = 1.44269504089f;
  const float SCALE = 0.125f * L2E;
  const float sl2 = slopes[h] * L2E;
  const size_t headSD = (size_t)bh * (S_ * D_);
  const size_t headDS = (size_t)bh * (D_ * S_);
  const int r8 = lane >> 3, c16 = (lane & 7) ^ r8;

  bfx8 qf[2];
  {
    const u16* qp = Q + headSD + (size_t)(w0 + q) * D_ + g * 8;
    qf[0] = *reinterpret_cast<const bfx8*>(qp);
    qf[1] = *reinterpret_cast<const bfx8*>(qp + 32);
  }
  bfx8 onesf;
#pragma unroll
  for (int jj = 0; jj < 8; ++jj) onesf[jj] = (__bf16)1.0f;
  f32x4 base[4];
#pragma unroll
  for (int nf = 0; nf < 4; ++nf)
#pragma unroll
    for (int r = 0; r < 4; ++r) base[nf][r] = sl2 * (float)(nf * 16 + 4 * g + r);
  const int ir0 = wave * 16 + q;  // diagonal-tile mask boundary

  float m = 0.f;
  f32x4 oT[4] = {};
  f32x4 oX = {};  // l accumulator (all components equal l)

  auto stage = [&](int t, int buf) {
#pragma unroll
    for (int i = 0; i < 2; ++i) {
      const int cc = wave * 2 + i;
      const int row = cc * 8 + r8;
      gload16(Kb + headSD + (size_t)t * 4096 + row * 64 + c16 * 8, (char*)sK[buf] + cc * 1024);
      gload16(Vt + headDS + (size_t)row * S_ + t * 64 + c16 * 8, (char*)sV[buf] + cc * 1024);
    }
  };

  stage(t0, 0);
  __syncthreads();
  int cur = 0;
  for (int t = t0; t < t1; ++t) {
    if (t + 1 < t1) stage(t + 1, cur ^ 1);
    const char* sKc = reinterpret_cast<const char*>(sK[cur]);
    const char* sVc = reinterpret_cast<const char*>(sV[cur]);
    f32x4 tt[4] = {};
    __builtin_amdgcn_s_setprio(1);
#pragma unroll
    for (int kc = 0; kc < 2; ++kc)
#pragma unroll
      for (int nf = 0; nf < 4; ++nf) {
        const bfx8 kf =
            *reinterpret_cast<const bfx8*>(sKc + swz128(((nf * 16 + q) << 7) + kc * 64 + (g << 4)));
        tt[nf] = __builtin_amdgcn_mfma_f32_16x16x32_bf16(kf, qf[kc], tt[nf], 0, 0, 0);
      }
    __builtin_amdgcn_s_setprio(0);
    const float tb = sl2 * (float)(t * 64);
    if (t != qi) {
      // ---- non-diagonal tile: raw max + upper bound, fused bias+exp2 ----
      float rmax = -3.0e38f;
#pragma unroll
      for (int nf = 0; nf < 4; ++nf)
#pragma unroll
        for (int r = 0; r < 4; ++r) rmax = fmaxf(rmax, tt[nf][r]);
      rmax = fmaxf(rmax, __shfl_xor(rmax, 16));
      rmax = fmaxf(rmax, __shfl_xor(rmax, 32));
      const float bound = fmaf(rmax, SCALE, tb + sl2 * 63.f);  // >= true biased row max
      if (!__all(bound <= m + 12.0f)) {
        const float mnew = fmaxf(m, bound);
        const float corr = __builtin_amdgcn_exp2f(m - mnew);
        m = mnew;
#pragma unroll
        for (int nf = 0; nf < 4; ++nf) oT[nf] *= corr;
        oX *= corr;
      }
      const float tbm = tb - m;
#pragma unroll
      for (int nf = 0; nf < 4; ++nf) {
        const f32x4 bb = base[nf] + tbm;
#pragma unroll
        for (int r = 0; r < 4; ++r)
          tt[nf][r] = __builtin_amdgcn_exp2f(fmaf(tt[nf][r], SCALE, bb[r]));
      }
    } else {
      // ---- diagonal tile: exact per-element bias + causal mask ----
      float rmax = -3.0e38f;
#pragma unroll
      for (int nf = 0; nf < 4; ++nf)
#pragma unroll
        for (int r = 0; r < 4; ++r) {
          float sv = fmaf(tt[nf][r], SCALE, base[nf][r] + tb);
          if (nf * 16 + 4 * g + r > ir0) sv = -3.0e38f;
          tt[nf][r] = sv;
          rmax = fmaxf(rmax, sv);
        }
      rmax = fmaxf(rmax, __shfl_xor(rmax, 16));
      rmax = fmaxf(rmax, __shfl_xor(rmax, 32));
      if (!__all(rmax <= m + 12.0f)) {
        const float mnew = fmaxf(m, rmax);
        const float corr = __builtin_amdgcn_exp2f(m - mnew);
        m = mnew;
#pragma unroll
        for (int nf = 0; nf < 4; ++nf) oT[nf] *= corr;
        oX *= corr;
      }
#pragma unroll
      for (int nf = 0; nf < 4; ++nf)
#pragma unroll
        for (int r = 0; r < 4; ++r) tt[nf][r] = __builtin_amdgcn_exp2f(tt[nf][r] - m);
    }
    // P -> wave-private swizzled sP; wave-internal lgkm ordering, no barrier
    char* pw = reinterpret_cast<char*>(sP[wave]);
#pragma unroll
    for (int nf = 0; nf < 4; ++nf) {
      bfx4 w = {(__bf16)tt[nf][0], (__bf16)tt[nf][1], (__bf16)tt[nf][2], (__bf16)tt[nf][3]};
      *reinterpret_cast<bfx4*>(pw + swz128((q << 7) + nf * 32 + g * 8)) = w;
    }
    bfx8 pa[2];
#pragma unroll
    for (int kc = 0; kc < 2; ++kc)
      pa[kc] = *reinterpret_cast<const bfx8*>(pw + swz128((q << 7) + kc * 64 + (g << 4)));
    __builtin_amdgcn_s_setprio(1);
#pragma unroll
    for (int kc = 0; kc < 2; ++kc) {
#pragma unroll
      for (int nf = 0; nf < 4; ++nf) {
        const bfx8 vf =
            *reinterpret_cast<const bfx8*>(sVc + swz128(((nf * 16 + q) << 7) + kc * 64 + (g << 4)));
        oT[nf] = __builtin_amdgcn_mfma_f32_16x16x32_bf16(vf, pa[kc], oT[nf], 0, 0, 0);
      }
      oX = __builtin_amdgcn_mfma_f32_16x16x32_bf16(onesf, pa[kc], oX, 0, 0, 0);  // l rides PV
    }
    __builtin_amdgcn_s_setprio(0);
    __syncthreads();
    cur ^= 1;
  }
  if (slot < 0) {
    const float rl = 1.0f / oX[0];
    const int row = w0 + q;
#pragma unroll
    for (int nf = 0; nf < 4; ++nf) {
      bfx4 w = {(__bf16)(oT[nf][0] * rl), (__bf16)(oT[nf][1] * rl), (__bf16)(oT[nf][2] * rl),
                (__bf16)(oT[nf][3] * rl)};
      const int col = h * 64 + nf * 16 + g * 4;
      *reinterpret_cast<bfx4*>(reinterpret_cast<char*>(Y) +
                               (((size_t)b * S_ + row) * E_ + col) * 2) = w;
    }
  } else {
    const int sg = bh * 48 + slot;
    u16* po = pO + (size_t)sg * 4096 + (size_t)(wave * 16 + q) * 64;
#pragma unroll
    for (int nf = 0; nf < 4; ++nf) {
      bfx4 w = {(__bf16)oT[nf][0], (__bf16)oT[nf][1], (__bf16)oT[nf][2], (__bf16)oT[nf][3]};
      *reinterpret_cast<bfx4*>(po + nf * 16 + g * 4) = w;
    }
    if (g == 0) {
      float2 ml = make_float2(m, oX[0]);
      reinterpret_cast<float2*>(pML)[sg * 64 + wave * 16 + q] = ml;
    }
  }
}

// ---------------- merge partial chunks: Y[rows] = sum_c w_c O_c / sum_c w_c l_c ----------------
__global__ __launch_bounds__(256) void merge_attn(const u16* __restrict__ pO,
                                                  const float* __restrict__ pML,
                                                  u16* __restrict__ Y) {
  const int mb = blockIdx.x;
  const int bh = mb / 20, qq = mb % 20, qi = 12 + qq;  // only qi>=12 are split
  const int nch = (qi < 24) ? 2 : 3;
  const int sb = (qi < 24) ? (qi - 12) * 2 : 24 + (qi - 24) * 3;
  const int b = bh >> 4, h = bh & 15;
  const int tid = threadIdx.x;
  const int r = tid >> 2, dq = (tid & 3) * 16;
  const float2* ml2 = reinterpret_cast<const float2*>(pML);
  float mm[3], ll[3];
  float M = -3.0e38f;
#pragma unroll
  for (int c = 0; c < 3; ++c) {
    if (c < nch) {
      const float2 v = ml2[(bh * 48 + sb + c) * 64 + r];
      mm[c] = v.x;
      ll[c] = v.y;
      M = fmaxf(M, v.x);
    } else {
      mm[c] = -3.0e38f;
      ll[c] = 0.f;
    }
  }
  float L = 0.f, acc[16];
#pragma unroll
  for (int i = 0; i < 16; ++i) acc[i] = 0.f;
#pragma unroll
  for (int c = 0; c < 3; ++c) {
    if (c < nch) {
      const float w = __builtin_amdgcn_exp2f(mm[c] - M);
      L += w * ll[c];
      const u16* src = pO + (size_t)(bh * 48 + sb + c) * 4096 + r * 64 + dq;
      const u16x8 a = *reinterpret_cast<const u16x8*>(src);
      const u16x8 bb = *reinterpret_cast<const u16x8*>(src + 8);
#pragma unroll
      for (int i = 0; i < 8; ++i) {
        acc[i] += w * __uint_as_float(((unsigned)a[i]) << 16);
        acc[8 + i] += w * __uint_as_float(((unsigned)bb[i]) << 16);
      }
    }
  }
  const float rl = 1.0f / L;
  u16x8 o0, o1;
#pragma unroll
  for (int i = 0; i < 8; ++i) {
    o0[i] = f2bf(acc[i] * rl);
    o1[i] = f2bf(acc[8 + i] * rl);
  }
  u16* dst = Y + ((size_t)b * S_ + qi * 64 + r) * E_ + h * 64 + dq;
  *reinterpret_cast<u16x8*>(dst) = o0;
  *reinterpret_cast<u16x8*>(dst + 8) = o1;
}

extern "C" void kernel_launch(void* const* d_in, const int* in_sizes, int n_in, void* d_out,
                              int out_size, void* d_ws, size_t ws_size, hipStream_t stream) {
  (void)in_sizes; (void)n_in; (void)out_size; (void)ws_size;
  const float* x = (const float*)d_in[0];
  const float* Wkqv = (const float*)d_in[1];
  const float* bkqv = (const float*)d_in[2];
  const float* Wproj = (const float*)d_in[3];
  const float* bproj = (const float*)d_in[4];
  const float* slopes = (const float*)d_in[5];
  float* out = (float*)d_out;

  const size_t MBE = (size_t)4096 * 1024;
  u16* xb = (u16*)d_ws;                       // x bf16              [4096][1024]
  u16* wkqvt = xb + MBE;                      // W_kqv^T bf16        [3072][1024]
  u16* wprojt = wkqvt + (size_t)3072 * 1024;  // W_proj^T bf16       [1024][1024]
  u16* kbuf = wprojt + (size_t)1024 * 1024;   // K   [B][H][S][D]
  u16* qbuf = kbuf + MBE;                     // Q   [B][H][S][D]
  u16* vtbuf = qbuf + MBE;                    // V^T [B][H][D][S]
  u16* ybuf = vtbuf + MBE;                    // attn out [B][S][E]
  // partial-chunk scratch overlays xb+wkqvt (dead after gemm_kqv): 12.6 MB O + 0.79 MB ml
  u16* pO = xb;                                      // [1536][64][64] bf16
  float* pML = (float*)(xb + (size_t)1536 * 4096);   // [1536][64][2] f32

  prep<<<dim3(3072), dim3(256), 0, stream>>>(x, Wkqv, Wproj, xb, wkqvt, wprojt);
  gemm_kqv<<<dim3(24, 32), dim3(256), 0, stream>>>(xb, wkqvt, bkqv, 4096, 3072, 1024, kbuf, qbuf,
                                                   vtbuf);
  attn_alibi<<<dim3(1920), dim3(256), 0, stream>>>(qbuf, kbuf, vtbuf, slopes, ybuf, pO, pML);
  merge_attn<<<dim3(640), dim3(256), 0, stream>>>(pO, pML, ybuf);
  gemm_proj<<<dim3(8, 32), dim3(512), 0, stream>>>(ybuf, wprojt, bproj, 4096, 1024, 1024, out);
}